// Round 11
// baseline (213.239 us; speedup 1.0000x reference)
//
#include <hip/hip_runtime.h>
#include <hip/hip_bf16.h>

#define D_MODEL 1024
#define NHEADS  16
#define HDIM    64
#define SEQ     2048
#define BATCH   2
#define MROWS   (BATCH * SEQ)   // 4096
#define CHELEM  ((size_t)BATCH * NHEADS * SEQ * HDIM)  // 4194304

typedef __bf16 bf16x8 __attribute__((ext_vector_type(8)));
typedef float  f32x4  __attribute__((ext_vector_type(4)));

__device__ __forceinline__ unsigned short f2bf(float f) {
  unsigned u = __builtin_bit_cast(unsigned, f);
  return (unsigned short)((u + 0x7fffu + ((u >> 16) & 1u)) >> 16);
}

__device__ __forceinline__ f32x4 mfma16(bf16x8 a, bf16x8 b, f32x4 c) {
  return __builtin_amdgcn_mfma_f32_16x16x32_bf16(a, b, c, 0, 0, 0);
}

__device__ __forceinline__ void gll16(const unsigned short* g, unsigned short* l) {
  __builtin_amdgcn_global_load_lds(
      (const __attribute__((address_space(1))) unsigned*)g,
      (__attribute__((address_space(3))) unsigned*)l, 16, 0, 0);
}

__global__ void cvt_f32_bf16(const float* __restrict__ in,
                             unsigned short* __restrict__ out, int n4) {
  int i = blockIdx.x * blockDim.x + threadIdx.x;
  if (i >= n4) return;
  float4 v = reinterpret_cast<const float4*>(in)[i];
  ushort4 o;
  o.x = f2bf(v.x); o.y = f2bf(v.y); o.z = f2bf(v.z); o.w = f2bf(v.w);
  reinterpret_cast<ushort4*>(out)[i] = o;
}

// fused conversion of the 4 weight matrices (saves 3 launches)
__global__ void cvt_w4(const float* __restrict__ s0, const float* __restrict__ s1,
                       const float* __restrict__ s2, const float* __restrict__ s3,
                       unsigned short* __restrict__ d0, unsigned short* __restrict__ d1,
                       unsigned short* __restrict__ d2, unsigned short* __restrict__ d3) {
  int i = blockIdx.x * blockDim.x + threadIdx.x;  // n4 = D*D/4
  const int y = blockIdx.y;
  const float* s = (y == 0) ? s0 : (y == 1) ? s1 : (y == 2) ? s2 : s3;
  unsigned short* d = (y == 0) ? d0 : (y == 1) ? d1 : (y == 2) ? d2 : d3;
  float4 v = reinterpret_cast<const float4*>(s)[i];
  ushort4 o;
  o.x = f2bf(v.x); o.y = f2bf(v.y); o.z = f2bf(v.z); o.w = f2bf(v.w);
  reinterpret_cast<ushort4*>(d)[i] = o;
}

// C = A[M,K] * Bt[N,K]^T + bias  (global_load_lds staging, m97 pattern)
// MODE 2: out f32 row-major [M,N]  (final projection, bias=b0)
// MODE 3: fused QKV: N=3072; chunk 0->Q [B,H,S,64] (PRE-SCALED by 0.125),
//         1->K [B,H,S,64], 2->V^T [B,H,64,S]; outp = base of Q
template <int MODE>
__global__ __launch_bounds__(256) void gemm_bt2(
    const unsigned short* __restrict__ A,
    const unsigned short* __restrict__ Bt,
    const float* __restrict__ b0, const float* __restrict__ b1,
    const float* __restrict__ b2,
    void* __restrict__ outp, int M, int N, int K) {
  __shared__ __align__(16) unsigned short lA[128 * 32];
  __shared__ __align__(16) unsigned short lB[128 * 32];
  const int tid = threadIdx.x;
  const int m0 = blockIdx.y * 128, n0 = blockIdx.x * 128;
  const int lane = tid & 63, wid = tid >> 6;
  const int wr = wid >> 1, wc = wid & 1;
  const int fr = lane & 15, g = lane >> 4;

  const int srow = wid * 32 + (lane >> 2);
  const int scol = (lane & 3) * 8;
  const unsigned short* gA = A + (size_t)(m0 + srow) * K + scol;
  const unsigned short* gB = Bt + (size_t)(n0 + srow) * K + scol;
  unsigned short* lAw = lA + wid * 1024;
  unsigned short* lBw = lB + wid * 1024;

  f32x4 acc[4][4];
#pragma unroll
  for (int i = 0; i < 4; ++i)
#pragma unroll
    for (int j = 0; j < 4; ++j) acc[i][j] = (f32x4){0.f, 0.f, 0.f, 0.f};

  for (int kt = 0; kt < K; kt += 32) {
    gll16(gA + kt, lAw);
    gll16(gA + (size_t)16 * K + kt, lAw + 512);
    gll16(gB + kt, lBw);
    gll16(gB + (size_t)16 * K + kt, lBw + 512);
    __syncthreads();
    bf16x8 af[4], bfv[4];
#pragma unroll
    for (int i = 0; i < 4; ++i)
      af[i] = *reinterpret_cast<const bf16x8*>(
          &lA[(wr * 64 + i * 16 + fr) * 32 + g * 8]);
#pragma unroll
    for (int j = 0; j < 4; ++j)
      bfv[j] = *reinterpret_cast<const bf16x8*>(
          &lB[(wc * 64 + j * 16 + fr) * 32 + g * 8]);
#pragma unroll
    for (int i = 0; i < 4; ++i)
#pragma unroll
      for (int j = 0; j < 4; ++j)
        acc[i][j] = mfma16(af[i], bfv[j], acc[i][j]);
    __syncthreads();
  }

  const int src = n0 >> 10;
  const float* bp = (MODE == 2) ? b0 : (src == 0 ? b0 : (src == 1 ? b1 : b2));
#pragma unroll
  for (int i = 0; i < 4; ++i)
#pragma unroll
    for (int j = 0; j < 4; ++j)
#pragma unroll
      for (int r = 0; r < 4; ++r) {
        int m = m0 + wr * 64 + i * 16 + g * 4 + r;
        int n = n0 + wc * 64 + j * 16 + fr;
        if (MODE == 2) {
          float val = acc[i][j][r] + bp[n];
          reinterpret_cast<float*>(outp)[(size_t)m * N + n] = val;
        } else {
          int within = n & 1023;
          float val = acc[i][j][r] + bp[within];
          if (src == 0) val *= 0.125f;  // fold softmax scale into Q (exact)
          int b = m >> 11, s = m & 2047;
          int hh = within >> 6, dh = within & 63;
          size_t idx;
          if (src != 2)
            idx = ((size_t)(b * NHEADS + hh) * SEQ + s) * HDIM + dh;
          else
            idx = ((size_t)(b * NHEADS + hh) * HDIM + dh) * SEQ + s;
          reinterpret_cast<unsigned short*>(outp)[(size_t)src * CHELEM + idx] =
              f2bf(val);
        }
      }
}

// Flash attention, split-K across wave pairs: waves A/B take even/odd k-tiles
// of the same mirror pair (qt, 127-qt) -> every wave runs 16 or 17 tiles,
// 4096 waves total (4/SIMD). Exact (m,l,O) merge through LDS, 2 barriers.
// XCD slab mapping kept (K/V L2-resident). Q pre-scaled by 0.125.
// Q,K: [B,H,S,64] bf16 ; Vt: [B,H,64,S] bf16 ; O: [B,S,1024] bf16
__global__ __launch_bounds__(256, 4) void attn_fwd8(
    const unsigned short* __restrict__ Q,
    const unsigned short* __restrict__ Km,
    const unsigned short* __restrict__ Vt,
    unsigned short* __restrict__ O) {
  const int tid = threadIdx.x;
  const int lane = tid & 63, wid = tid >> 6;
  const int fr = lane & 15, g = lane >> 4;
  // XCD-grouped decode: lin%8 = XCD; 32 blocks per (b,h) slab on one XCD.
  const int lin = blockIdx.x;            // 0..1023
  const int c = lin & 7;
  const int t = lin >> 3;                // 0..127
  const int pgidx = t & 31;              // 0..31
  const int sgrp = t >> 5;               // 0..3
  const int slab = sgrp * 8 + c;         // 0..31
  const int b = slab >> 4, h = slab & 15;
  const int bh = b * NHEADS + h;
  const int pairq = pgidx * 2 + (wid >> 1);  // 0..63
  const int rho = wid & 1;               // 0 = wave A, 1 = wave B

  __shared__ __align__(16) unsigned short pl[4][16 * 64];  // P tiles, swizzled
  __shared__ __align__(16) char mergebuf[2][6144];         // per-pair (m,l,O)
  char* plw = reinterpret_cast<char*>(pl[wid]);
  char* R = mergebuf[wid >> 1];

  const unsigned short* kptr = Km + (size_t)bh * SEQ * HDIM;
  const unsigned short* vptr = Vt + (size_t)bh * HDIM * SEQ;

// ---- round-8 proven tile body (stride-2 k-loop) ----
#define RUN_PASS(Q0, NKT, KSTART)                                           \
  for (int kt = (KSTART); kt < (NKT); kt += 2) {                            \
    const int n0 = kt * 64;                                                 \
    const unsigned short* kp = kptr + (size_t)(n0 + fr) * HDIM + g * 8;     \
    bf16x8 kf0[4], kf1[4];                                                  \
    _Pragma("unroll") for (int cc = 0; cc < 4; ++cc) {                      \
      kf0[cc] = *reinterpret_cast<const bf16x8*>(kp + cc * 16 * HDIM);      \
      kf1[cc] = *reinterpret_cast<const bf16x8*>(kp + cc * 16 * HDIM + 32); \
    }                                                                       \
    bf16x8 vf[2][4];                                                        \
    _Pragma("unroll") for (int nf = 0; nf < 4; ++nf) {                      \
      const unsigned short* vp =                                            \
          vptr + (size_t)(nf * 16 + fr) * SEQ + n0 + g * 8;                 \
      vf[0][nf] = *reinterpret_cast<const bf16x8*>(vp);                     \
      vf[1][nf] = *reinterpret_cast<const bf16x8*>(vp + 32);                \
    }                                                                       \
    f32x4 s[4];                                                             \
    __builtin_amdgcn_s_setprio(1);                                          \
    _Pragma("unroll") for (int cc = 0; cc < 4; ++cc) {                      \
      s[cc] = (f32x4){0.f, 0.f, 0.f, 0.f};                                  \
      s[cc] = mfma16(qa0, kf0[cc], s[cc]);                                  \
      s[cc] = mfma16(qa1, kf1[cc], s[cc]);                                  \
    }                                                                       \
    __builtin_amdgcn_s_setprio(0);                                          \
    float sv[4][4];                                                         \
    float lmax = -3e30f;                                                    \
    if (kt == (NKT) - 1) {                                                  \
      _Pragma("unroll") for (int cc = 0; cc < 4; ++cc)                      \
      _Pragma("unroll") for (int r = 0; r < 4; ++r) {                       \
        sv[cc][r] = (n0 + cc * 16 + fr <= (Q0) + g * 4 + r)                 \
                        ? s[cc][r] : -1e30f;                                \
        lmax = fmaxf(lmax, sv[cc][r]);                                      \
      }                                                                     \
    } else {                                                                \
      _Pragma("unroll") for (int cc = 0; cc < 4; ++cc)                      \
      _Pragma("unroll") for (int r = 0; r < 4; ++r) {                       \
        sv[cc][r] = s[cc][r];                                               \
        lmax = fmaxf(lmax, sv[cc][r]);                                      \
      }                                                                     \
    }                                                                       \
    if (!__all(lmax - mtile <= 8.0f)) {                                     \
      _Pragma("unroll") for (int r = 0; r < 4; ++r) {                       \
        float tm = fmaxf(fmaxf(sv[0][r], sv[1][r]),                         \
                         fmaxf(sv[2][r], sv[3][r]));                        \
        _Pragma("unroll") for (int msk = 1; msk < 16; msk <<= 1)            \
            tm = fmaxf(tm, __shfl_xor(tm, msk, 64));                        \
        const float mn = fmaxf(mreg[r], tm);                                \
        const float al = __expf(mreg[r] - mn);                              \
        mreg[r] = mn;                                                       \
        lrow[r] *= al;                                                      \
        _Pragma("unroll") for (int nf = 0; nf < 4; ++nf)                    \
            oacc[nf][r] *= al;                                              \
      }                                                                     \
      mtile = fminf(fminf(mreg[0], mreg[1]), fminf(mreg[2], mreg[3]));      \
    }                                                                       \
    _Pragma("unroll") for (int r = 0; r < 4; ++r) {                         \
      const int rl = g * 4 + r;                                             \
      _Pragma("unroll") for (int cc = 0; cc < 4; ++cc) {                    \
        float p = __expf(sv[cc][r] - mreg[r]);                              \
        lrow[r] += p;                                                       \
        int byte = (rl * 128 + (cc * 16 + fr) * 2) ^ ((rl & 7) << 4);       \
        *reinterpret_cast<unsigned short*>(plw + byte) = f2bf(p);           \
      }                                                                     \
    }                                                                       \
    __builtin_amdgcn_s_setprio(1);                                          \
    _Pragma("unroll") for (int blk = 0; blk < 2; ++blk) {                   \
      int byte = (fr * 128 + blk * 64 + g * 16) ^ ((fr & 7) << 4);          \
      bf16x8 pa = *reinterpret_cast<const bf16x8*>(plw + byte);             \
      _Pragma("unroll") for (int nf = 0; nf < 4; ++nf)                      \
          oacc[nf] = mfma16(pa, vf[blk][nf], oacc[nf]);                     \
    }                                                                       \
    __builtin_amdgcn_s_setprio(0);                                          \
  }

#define WRITE_STATE()                                                       \
  { _Pragma("unroll") for (int nf = 0; nf < 4; ++nf)                        \
        *reinterpret_cast<f32x4*>(R + lane * 64 + nf * 16) = oacc[nf];      \
    f32x4 m4_ = {mreg[0], mreg[1], mreg[2], mreg[3]};                       \
    f32x4 l4_ = {lrow[0], lrow[1], lrow[2], lrow[3]};                       \
    *reinterpret_cast<f32x4*>(R + 4096 + lane * 32) = m4_;                  \
    *reinterpret_cast<f32x4*>(R + 4096 + lane * 32 + 16) = l4_; }

#define MERGE_STORE(Q0)                                                     \
  { f32x4 mo_ = *reinterpret_cast<const f32x4*>(R + 4096 + lane * 32);      \
    f32x4 lo_ = *reinterpret_cast<const f32x4*>(R + 4096 + lane * 32 + 16); \
    f32x4 oo_[4];                                                           \
    _Pragma("unroll") for (int nf = 0; nf < 4; ++nf)                        \
        oo_[nf] = *reinterpret_cast<const f32x4*>(R + lane * 64 + nf * 16); \
    _Pragma("unroll") for (int r = 0; r < 4; ++r) {                         \
      const float M_ = fmaxf(mreg[r], mo_[r]);                              \
      const float aS_ = __expf(mreg[r] - M_);                               \
      const float aO_ = __expf(mo_[r] - M_);                                \
      float ls = lrow[r] * aS_ + lo_[r] * aO_;                              \
      _Pragma("unroll") for (int msk = 1; msk < 16; msk <<= 1)              \
          ls += __shfl_xor(ls, msk, 64);                                    \
      const float inv = 1.f / ls;                                           \
      const size_t base =                                                   \
          ((size_t)b * SEQ + (Q0) + g * 4 + r) * D_MODEL + h * HDIM;        \
      _Pragma("unroll") for (int nf = 0; nf < 4; ++nf)                      \
          O[base + nf * 16 + fr] =                                          \
              f2bf((oacc[nf][r] * aS_ + oo_[nf][r] * aO_) * inv);           \
    } }

  // ---------------- pass 0: q-tile = pairq (lower half) ----------------
  {
    const int qt = pairq;
    const int q0 = qt * 16;
    const int nkt = (qt >> 2) + 1;
    const unsigned short* qb = Q + ((size_t)bh * SEQ + q0 + fr) * HDIM + g * 8;
    bf16x8 qa0 = *reinterpret_cast<const bf16x8*>(qb);
    bf16x8 qa1 = *reinterpret_cast<const bf16x8*>(qb + 32);
    f32x4 oacc[4];
#pragma unroll
    for (int i = 0; i < 4; ++i) oacc[i] = (f32x4){0.f, 0.f, 0.f, 0.f};
    float mreg[4] = {-3e30f, -3e30f, -3e30f, -3e30f};
    float lrow[4] = {0.f, 0.f, 0.f, 0.f};
    float mtile = -3e30f;
    RUN_PASS(q0, nkt, rho);
    if (rho == 1) WRITE_STATE();
    __syncthreads();
    if (rho == 0) MERGE_STORE(q0);
  }
  // ---------------- pass 1: q-tile = 127 - pairq (upper half) -----------
  {
    const int qt = 127 - pairq;
    const int q0 = qt * 16;
    const int nkt = (qt >> 2) + 1;
    const unsigned short* qb = Q + ((size_t)bh * SEQ + q0 + fr) * HDIM + g * 8;
    bf16x8 qa0 = *reinterpret_cast<const bf16x8*>(qb);
    bf16x8 qa1 = *reinterpret_cast<const bf16x8*>(qb + 32);
    f32x4 oacc[4];
#pragma unroll
    for (int i = 0; i < 4; ++i) oacc[i] = (f32x4){0.f, 0.f, 0.f, 0.f};
    float mreg[4] = {-3e30f, -3e30f, -3e30f, -3e30f};
    float lrow[4] = {0.f, 0.f, 0.f, 0.f};
    float mtile = -3e30f;
    RUN_PASS(q0, nkt, rho ^ 1);
    if (rho == 0) WRITE_STATE();
    __syncthreads();
    if (rho == 1) MERGE_STORE(q0);
  }
#undef RUN_PASS
#undef WRITE_STATE
#undef MERGE_STORE
}

extern "C" void kernel_launch(void* const* d_in, const int* in_sizes, int n_in,
                              void* d_out, int out_size, void* d_ws,
                              size_t ws_size, hipStream_t stream) {
  const float* x  = (const float*)d_in[0];
  const float* wq = (const float*)d_in[1];
  const float* bq = (const float*)d_in[2];
  const float* wk = (const float*)d_in[3];
  const float* bk = (const float*)d_in[4];
  const float* wv = (const float*)d_in[5];
  const float* bv = (const float*)d_in[6];
  const float* wo = (const float*)d_in[7];
  const float* bo = (const float*)d_in[8];
  float* out = (float*)d_out;

  char* w = (char*)d_ws;
  unsigned short* xb    = (unsigned short*)w; w += (size_t)MROWS * D_MODEL * 2;
  unsigned short* wqkvb = (unsigned short*)w; w += (size_t)3 * D_MODEL * D_MODEL * 2;
  unsigned short* wob   = (unsigned short*)w; w += (size_t)D_MODEL * D_MODEL * 2;
  unsigned short* Qb    = (unsigned short*)w; w += CHELEM * 2 * 3;  // Q,K,Vt
  unsigned short* Ob    = (unsigned short*)w; w += (size_t)MROWS * D_MODEL * 2;
  unsigned short* Kb  = Qb + CHELEM;
  unsigned short* Vtb = Qb + 2 * CHELEM;

  {
    int n4 = MROWS * D_MODEL / 4;
    cvt_f32_bf16<<<n4 / 256, 256, 0, stream>>>(x, xb, n4);
  }
  {
    int n4 = D_MODEL * D_MODEL / 4;  // 262144 -> 1024 blocks x 4
    cvt_w4<<<dim3(n4 / 256, 4), 256, 0, stream>>>(
        wq, wk, wv, wo, wqkvb, wqkvb + (size_t)D_MODEL * D_MODEL,
        wqkvb + (size_t)2 * D_MODEL * D_MODEL, wob);
  }

  // fused QKV projection: N = 3072
  gemm_bt2<3><<<dim3(3 * D_MODEL / 128, MROWS / 128), 256, 0, stream>>>(
      xb, wqkvb, bq, bk, bv, Qb, MROWS, 3 * D_MODEL, D_MODEL);

  attn_fwd8<<<1024, 256, 0, stream>>>(Qb, Kb, Vtb, Ob);

  gemm_bt2<2><<<dim3(D_MODEL / 128, MROWS / 128), 256, 0, stream>>>(
      Ob, wob, bo, bo, bo, out, MROWS, D_MODEL, D_MODEL);
}

// Round 12
// 133.589 us; speedup vs baseline: 1.5962x; 1.5962x over previous
//
#include <hip/hip_runtime.h>
#include <hip/hip_bf16.h>

#define D_MODEL 1024
#define NHEADS  16
#define HDIM    64
#define SEQ     2048
#define BATCH   2
#define MROWS   (BATCH * SEQ)   // 4096
#define CHELEM  ((size_t)BATCH * NHEADS * SEQ * HDIM)  // 4194304

typedef __bf16 bf16x8 __attribute__((ext_vector_type(8)));
typedef float  f32x4  __attribute__((ext_vector_type(4)));

__device__ __forceinline__ unsigned short f2bf(float f) {
  unsigned u = __builtin_bit_cast(unsigned, f);
  return (unsigned short)((u + 0x7fffu + ((u >> 16) & 1u)) >> 16);
}

__device__ __forceinline__ f32x4 mfma16(bf16x8 a, bf16x8 b, f32x4 c) {
  return __builtin_amdgcn_mfma_f32_16x16x32_bf16(a, b, c, 0, 0, 0);
}

__device__ __forceinline__ void gll16(const unsigned short* g, unsigned short* l) {
  __builtin_amdgcn_global_load_lds(
      (const __attribute__((address_space(1))) unsigned*)g,
      (__attribute__((address_space(3))) unsigned*)l, 16, 0, 0);
}

__global__ void cvt_f32_bf16(const float* __restrict__ in,
                             unsigned short* __restrict__ out, int n4) {
  int i = blockIdx.x * blockDim.x + threadIdx.x;
  if (i >= n4) return;
  float4 v = reinterpret_cast<const float4*>(in)[i];
  ushort4 o;
  o.x = f2bf(v.x); o.y = f2bf(v.y); o.z = f2bf(v.z); o.w = f2bf(v.w);
  reinterpret_cast<ushort4*>(out)[i] = o;
}

// fused conversion of the 4 weight matrices (saves 3 launches)
__global__ void cvt_w4(const float* __restrict__ s0, const float* __restrict__ s1,
                       const float* __restrict__ s2, const float* __restrict__ s3,
                       unsigned short* __restrict__ d0, unsigned short* __restrict__ d1,
                       unsigned short* __restrict__ d2, unsigned short* __restrict__ d3) {
  int i = blockIdx.x * blockDim.x + threadIdx.x;  // n4 = D*D/4
  const int y = blockIdx.y;
  const float* s = (y == 0) ? s0 : (y == 1) ? s1 : (y == 2) ? s2 : s3;
  unsigned short* d = (y == 0) ? d0 : (y == 1) ? d1 : (y == 2) ? d2 : d3;
  float4 v = reinterpret_cast<const float4*>(s)[i];
  ushort4 o;
  o.x = f2bf(v.x); o.y = f2bf(v.y); o.z = f2bf(v.z); o.w = f2bf(v.w);
  reinterpret_cast<ushort4*>(d)[i] = o;
}

// C = A[M,K] * Bt[N,K]^T + bias  (global_load_lds staging, m97 pattern)
// MODE 2: out f32 row-major [M,N]  (final projection, bias=b0)
// MODE 3: fused QKV: N=3072; chunk 0->Q [B,H,S,64] (PRE-SCALED by 0.125),
//         1->K [B,H,S,64], 2->V^T [B,H,64,S]; outp = base of Q
template <int MODE>
__global__ __launch_bounds__(256) void gemm_bt2(
    const unsigned short* __restrict__ A,
    const unsigned short* __restrict__ Bt,
    const float* __restrict__ b0, const float* __restrict__ b1,
    const float* __restrict__ b2,
    void* __restrict__ outp, int M, int N, int K) {
  __shared__ __align__(16) unsigned short lA[128 * 32];
  __shared__ __align__(16) unsigned short lB[128 * 32];
  const int tid = threadIdx.x;
  const int m0 = blockIdx.y * 128, n0 = blockIdx.x * 128;
  const int lane = tid & 63, wid = tid >> 6;
  const int wr = wid >> 1, wc = wid & 1;
  const int fr = lane & 15, g = lane >> 4;

  const int srow = wid * 32 + (lane >> 2);
  const int scol = (lane & 3) * 8;
  const unsigned short* gA = A + (size_t)(m0 + srow) * K + scol;
  const unsigned short* gB = Bt + (size_t)(n0 + srow) * K + scol;
  unsigned short* lAw = lA + wid * 1024;
  unsigned short* lBw = lB + wid * 1024;

  f32x4 acc[4][4];
#pragma unroll
  for (int i = 0; i < 4; ++i)
#pragma unroll
    for (int j = 0; j < 4; ++j) acc[i][j] = (f32x4){0.f, 0.f, 0.f, 0.f};

  for (int kt = 0; kt < K; kt += 32) {
    gll16(gA + kt, lAw);
    gll16(gA + (size_t)16 * K + kt, lAw + 512);
    gll16(gB + kt, lBw);
    gll16(gB + (size_t)16 * K + kt, lBw + 512);
    __syncthreads();
    bf16x8 af[4], bfv[4];
#pragma unroll
    for (int i = 0; i < 4; ++i)
      af[i] = *reinterpret_cast<const bf16x8*>(
          &lA[(wr * 64 + i * 16 + fr) * 32 + g * 8]);
#pragma unroll
    for (int j = 0; j < 4; ++j)
      bfv[j] = *reinterpret_cast<const bf16x8*>(
          &lB[(wc * 64 + j * 16 + fr) * 32 + g * 8]);
#pragma unroll
    for (int i = 0; i < 4; ++i)
#pragma unroll
      for (int j = 0; j < 4; ++j)
        acc[i][j] = mfma16(af[i], bfv[j], acc[i][j]);
    __syncthreads();
  }

  const int src = n0 >> 10;
  const float* bp = (MODE == 2) ? b0 : (src == 0 ? b0 : (src == 1 ? b1 : b2));
#pragma unroll
  for (int i = 0; i < 4; ++i)
#pragma unroll
    for (int j = 0; j < 4; ++j)
#pragma unroll
      for (int r = 0; r < 4; ++r) {
        int m = m0 + wr * 64 + i * 16 + g * 4 + r;
        int n = n0 + wc * 64 + j * 16 + fr;
        if (MODE == 2) {
          float val = acc[i][j][r] + bp[n];
          reinterpret_cast<float*>(outp)[(size_t)m * N + n] = val;
        } else {
          int within = n & 1023;
          float val = acc[i][j][r] + bp[within];
          if (src == 0) val *= 0.125f;  // fold softmax scale into Q (exact)
          int b = m >> 11, s = m & 2047;
          int hh = within >> 6, dh = within & 63;
          size_t idx;
          if (src != 2)
            idx = ((size_t)(b * NHEADS + hh) * SEQ + s) * HDIM + dh;
          else
            idx = ((size_t)(b * NHEADS + hh) * HDIM + dh) * SEQ + s;
          reinterpret_cast<unsigned short*>(outp)[(size_t)src * CHELEM + idx] =
              f2bf(val);
        }
      }
}

// Flash attention, block-cooperative LDS-staged K/V (m97 schedule):
// block j of a (b,h) slab runs pass0 q-tiles {4j..4j+3} (nkt=j+1) and pass1
// q-tiles {124-4j..127-4j} (nkt=32-j) -> all 4 waves same trip count, all
// blocks 33 tiles total. K/V staged once per block per tile via gll16 with
// PRE-SWIZZLED global source (m173), double-buffered, 1 barrier/tile.
// Fragments read from LDS with the proven XOR swizzle. Defer-max softmax.
// Q,K: [B,H,S,64] bf16 ; Vt: [B,H,64,S] bf16 ; O: [B,S,1024] bf16
__global__ __launch_bounds__(256) void attn_fwd9(
    const unsigned short* __restrict__ Q,
    const unsigned short* __restrict__ Km,
    const unsigned short* __restrict__ Vt,
    unsigned short* __restrict__ O) {
  const int tid = threadIdx.x;
  const int lane = tid & 63, wid = tid >> 6;
  const int fr = lane & 15, g = lane >> 4;
  // XCD-grouped decode: lin%8 = XCD; 16 blocks per (b,h) slab on one XCD.
  const int lin = blockIdx.x;            // 0..511
  const int c = lin & 7;
  const int t = lin >> 3;                // 0..63
  const int j = t & 15;                  // block's pair index 0..15
  const int sgrp = t >> 4;               // 0..3
  const int slab = sgrp * 8 + c;         // 0..31
  const int b = slab >> 4, h = slab & 15;
  const int bh = b * NHEADS + h;

  __shared__ __align__(16) unsigned short lK[2][4096];   // 2 x 8KB, swizzled
  __shared__ __align__(16) unsigned short lV[2][4096];   // 2 x 8KB, swizzled
  __shared__ __align__(16) unsigned short pl[4][1024];   // P tiles, swizzled
  char* plw = reinterpret_cast<char*>(pl[wid]);

  const unsigned short* kptr = Km + (size_t)bh * SEQ * HDIM;
  const unsigned short* vptr = Vt + (size_t)bh * HDIM * SEQ;

  // staging constants: thread t covers rows sr0 (rd=0) and sr0+32 (rd=1),
  // chunk sch; source chunk pre-swizzled so linear LDS == XOR layout.
  const int sr0 = tid >> 3;              // 0..31
  const int sch = tid & 7;
  const int schx = ((sch ^ (sr0 & 7)) << 3);  // elem offset of 16B chunk
  // fragment-read swizzled chunk offsets (elem units)
  const int kswz0 = ((g ^ (fr & 7)) << 3);        // ch = g
  const int kswz1 = (((4 + g) ^ (fr & 7)) << 3);  // ch = 4+g

#define STAGE(BI, N0)                                                       \
  { gll16(kptr + (size_t)((N0) + sr0) * HDIM + schx, &lK[BI][wid * 512]);   \
    gll16(kptr + (size_t)((N0) + sr0 + 32) * HDIM + schx,                   \
          &lK[BI][2048 + wid * 512]);                                       \
    gll16(vptr + (size_t)sr0 * SEQ + (N0) + schx, &lV[BI][wid * 512]);      \
    gll16(vptr + (size_t)(sr0 + 32) * SEQ + (N0) + schx,                    \
          &lV[BI][2048 + wid * 512]); }

#pragma unroll 1
  for (int pass = 0; pass < 2; ++pass) {
    const int qt = pass ? (124 - 4 * j + wid) : (4 * j + wid);
    const int q0 = qt * 16;
    const int nkt = pass ? (32 - j) : (j + 1);  // same for all 4 waves

    const unsigned short* qb = Q + ((size_t)bh * SEQ + q0 + fr) * HDIM + g * 8;
    bf16x8 qa0 = *reinterpret_cast<const bf16x8*>(qb);
    bf16x8 qa1 = *reinterpret_cast<const bf16x8*>(qb + 32);

    f32x4 oacc[4];
#pragma unroll
    for (int i = 0; i < 4; ++i) oacc[i] = (f32x4){0.f, 0.f, 0.f, 0.f};
    float mreg[4] = {-3e30f, -3e30f, -3e30f, -3e30f};
    float lrow[4] = {0.f, 0.f, 0.f, 0.f};
    float mtile = -3e30f;

    STAGE(0, 0);
    __syncthreads();

    for (int kt = 0; kt < nkt; ++kt) {
      const int bi = kt & 1;
      if (kt + 1 < nkt) STAGE(bi ^ 1, (kt + 1) * 64);
      const int n0 = kt * 64;
      // K fragments from swizzled LDS: key = n0 + c*16 + fr
      bf16x8 kf0[4], kf1[4];
#pragma unroll
      for (int cc = 0; cc < 4; ++cc) {
        kf0[cc] = *reinterpret_cast<const bf16x8*>(
            &lK[bi][(cc * 16 + fr) * 64 + kswz0]);
        kf1[cc] = *reinterpret_cast<const bf16x8*>(
            &lK[bi][(cc * 16 + fr) * 64 + kswz1]);
      }
      f32x4 s[4];
#pragma unroll
      for (int cc = 0; cc < 4; ++cc) {
        s[cc] = (f32x4){0.f, 0.f, 0.f, 0.f};
        s[cc] = mfma16(qa0, kf0[cc], s[cc]);
        s[cc] = mfma16(qa1, kf1[cc], s[cc]);
      }
      // (last-tile-only) mask, per-lane max
      float sv[4][4];
      float lmax = -3e30f;
      if (kt == nkt - 1) {
#pragma unroll
        for (int cc = 0; cc < 4; ++cc)
#pragma unroll
          for (int r = 0; r < 4; ++r) {
            sv[cc][r] = (n0 + cc * 16 + fr <= q0 + g * 4 + r) ? s[cc][r]
                                                              : -1e30f;
            lmax = fmaxf(lmax, sv[cc][r]);
          }
      } else {
#pragma unroll
        for (int cc = 0; cc < 4; ++cc)
#pragma unroll
          for (int r = 0; r < 4; ++r) {
            sv[cc][r] = s[cc][r];
            lmax = fmaxf(lmax, sv[cc][r]);
          }
      }
      // defer-max rescale (rare path)
      if (!__all(lmax - mtile <= 8.0f)) {
#pragma unroll
        for (int r = 0; r < 4; ++r) {
          float tm = fmaxf(fmaxf(sv[0][r], sv[1][r]), fmaxf(sv[2][r], sv[3][r]));
#pragma unroll
          for (int msk = 1; msk < 16; msk <<= 1)
            tm = fmaxf(tm, __shfl_xor(tm, msk, 64));
          const float mn = fmaxf(mreg[r], tm);
          const float al = __expf(mreg[r] - mn);
          mreg[r] = mn;
          lrow[r] *= al;
#pragma unroll
          for (int nf = 0; nf < 4; ++nf) oacc[nf][r] *= al;
        }
        mtile = fminf(fminf(mreg[0], mreg[1]), fminf(mreg[2], mreg[3]));
      }
      // P = exp(sv - m); per-lane partial sum; store to swizzled P tile
#pragma unroll
      for (int r = 0; r < 4; ++r) {
        const int rl = g * 4 + r;
#pragma unroll
        for (int cc = 0; cc < 4; ++cc) {
          float p = __expf(sv[cc][r] - mreg[r]);
          lrow[r] += p;
          int byte = (rl * 128 + (cc * 16 + fr) * 2) ^ ((rl & 7) << 4);
          *reinterpret_cast<unsigned short*>(plw + byte) = f2bf(p);
        }
      }
      // PV from LDS: P A-frag + V B-frags (swizzled reads)
#pragma unroll
      for (int blk = 0; blk < 2; ++blk) {
        int byte = (fr * 128 + blk * 64 + g * 16) ^ ((fr & 7) << 4);
        bf16x8 pa = *reinterpret_cast<const bf16x8*>(plw + byte);
        const int vs = blk ? kswz1 : kswz0;
#pragma unroll
        for (int nf = 0; nf < 4; ++nf) {
          bf16x8 vfr = *reinterpret_cast<const bf16x8*>(
              &lV[bi][(nf * 16 + fr) * 64 + vs]);
          oacc[nf] = mfma16(pa, vfr, oacc[nf]);
        }
      }
      __syncthreads();  // staged kt+1 complete; reads of buf bi done
    }

#pragma unroll
    for (int r = 0; r < 4; ++r) {
      float ls = lrow[r];
#pragma unroll
      for (int msk = 1; msk < 16; msk <<= 1) ls += __shfl_xor(ls, msk, 64);
      const float inv = 1.f / ls;
      const size_t base =
          ((size_t)b * SEQ + q0 + g * 4 + r) * D_MODEL + h * HDIM;
#pragma unroll
      for (int nf = 0; nf < 4; ++nf)
        O[base + nf * 16 + fr] = f2bf(oacc[nf][r] * inv);
    }
  }
#undef STAGE
}

extern "C" void kernel_launch(void* const* d_in, const int* in_sizes, int n_in,
                              void* d_out, int out_size, void* d_ws,
                              size_t ws_size, hipStream_t stream) {
  const float* x  = (const float*)d_in[0];
  const float* wq = (const float*)d_in[1];
  const float* bq = (const float*)d_in[2];
  const float* wk = (const float*)d_in[3];
  const float* bk = (const float*)d_in[4];
  const float* wv = (const float*)d_in[5];
  const float* bv = (const float*)d_in[6];
  const float* wo = (const float*)d_in[7];
  const float* bo = (const float*)d_in[8];
  float* out = (float*)d_out;

  char* w = (char*)d_ws;
  unsigned short* xb    = (unsigned short*)w; w += (size_t)MROWS * D_MODEL * 2;
  unsigned short* wqkvb = (unsigned short*)w; w += (size_t)3 * D_MODEL * D_MODEL * 2;
  unsigned short* wob   = (unsigned short*)w; w += (size_t)D_MODEL * D_MODEL * 2;
  unsigned short* Qb    = (unsigned short*)w; w += CHELEM * 2 * 3;  // Q,K,Vt
  unsigned short* Ob    = (unsigned short*)w; w += (size_t)MROWS * D_MODEL * 2;
  unsigned short* Kb  = Qb + CHELEM;
  unsigned short* Vtb = Qb + 2 * CHELEM;

  {
    int n4 = MROWS * D_MODEL / 4;
    cvt_f32_bf16<<<n4 / 256, 256, 0, stream>>>(x, xb, n4);
  }
  {
    int n4 = D_MODEL * D_MODEL / 4;  // 262144 -> 1024 blocks x 4
    cvt_w4<<<dim3(n4 / 256, 4), 256, 0, stream>>>(
        wq, wk, wv, wo, wqkvb, wqkvb + (size_t)D_MODEL * D_MODEL,
        wqkvb + (size_t)2 * D_MODEL * D_MODEL, wob);
  }

  // fused QKV projection: N = 3072
  gemm_bt2<3><<<dim3(3 * D_MODEL / 128, MROWS / 128), 256, 0, stream>>>(
      xb, wqkvb, bq, bk, bv, Qb, MROWS, 3 * D_MODEL, D_MODEL);

  attn_fwd9<<<512, 256, 0, stream>>>(Qb, Kb, Vtb, Ob);

  gemm_bt2<2><<<dim3(D_MODEL / 128, MROWS / 128), 256, 0, stream>>>(
      Ob, wob, bo, bo, bo, out, MROWS, D_MODEL, D_MODEL);
}

// Round 13
// 132.520 us; speedup vs baseline: 1.6091x; 1.0081x over previous
//
#include <hip/hip_runtime.h>
#include <hip/hip_bf16.h>

#define D_MODEL 1024
#define NHEADS  16
#define HDIM    64
#define SEQ     2048
#define BATCH   2
#define MROWS   (BATCH * SEQ)   // 4096
#define CHELEM  ((size_t)BATCH * NHEADS * SEQ * HDIM)  // 4194304

typedef __bf16 bf16x8 __attribute__((ext_vector_type(8)));
typedef float  f32x4  __attribute__((ext_vector_type(4)));

__device__ __forceinline__ unsigned short f2bf(float f) {
  unsigned u = __builtin_bit_cast(unsigned, f);
  return (unsigned short)((u + 0x7fffu + ((u >> 16) & 1u)) >> 16);
}

__device__ __forceinline__ float fexp2(float x) {
#if __has_builtin(__builtin_amdgcn_exp2f)
  return __builtin_amdgcn_exp2f(x);
#else
  return __expf(x * 0.6931471805599453f);
#endif
}

__device__ __forceinline__ f32x4 mfma16(bf16x8 a, bf16x8 b, f32x4 c) {
  return __builtin_amdgcn_mfma_f32_16x16x32_bf16(a, b, c, 0, 0, 0);
}

__device__ __forceinline__ void gll16(const unsigned short* g, unsigned short* l) {
  __builtin_amdgcn_global_load_lds(
      (const __attribute__((address_space(1))) unsigned*)g,
      (__attribute__((address_space(3))) unsigned*)l, 16, 0, 0);
}

__global__ void cvt_f32_bf16(const float* __restrict__ in,
                             unsigned short* __restrict__ out, int n4) {
  int i = blockIdx.x * blockDim.x + threadIdx.x;
  if (i >= n4) return;
  float4 v = reinterpret_cast<const float4*>(in)[i];
  ushort4 o;
  o.x = f2bf(v.x); o.y = f2bf(v.y); o.z = f2bf(v.z); o.w = f2bf(v.w);
  reinterpret_cast<ushort4*>(out)[i] = o;
}

// fused conversion of the 4 weight matrices (saves 3 launches)
__global__ void cvt_w4(const float* __restrict__ s0, const float* __restrict__ s1,
                       const float* __restrict__ s2, const float* __restrict__ s3,
                       unsigned short* __restrict__ d0, unsigned short* __restrict__ d1,
                       unsigned short* __restrict__ d2, unsigned short* __restrict__ d3) {
  int i = blockIdx.x * blockDim.x + threadIdx.x;  // n4 = D*D/4
  const int y = blockIdx.y;
  const float* s = (y == 0) ? s0 : (y == 1) ? s1 : (y == 2) ? s2 : s3;
  unsigned short* d = (y == 0) ? d0 : (y == 1) ? d1 : (y == 2) ? d2 : d3;
  float4 v = reinterpret_cast<const float4*>(s)[i];
  ushort4 o;
  o.x = f2bf(v.x); o.y = f2bf(v.y); o.z = f2bf(v.z); o.w = f2bf(v.w);
  reinterpret_cast<ushort4*>(d)[i] = o;
}

// C = A[M,K] * Bt[N,K]^T + bias  (global_load_lds staging, m97 pattern)
// MODE 2: out f32 row-major [M,N]  (final projection, bias=b0)
// MODE 3: fused QKV: N=3072; chunk 0->Q [B,H,S,64] (PRE-SCALED by
//         0.125*log2e for exp2-domain softmax), 1->K, 2->V^T [B,H,64,S]
template <int MODE>
__global__ __launch_bounds__(256) void gemm_bt2(
    const unsigned short* __restrict__ A,
    const unsigned short* __restrict__ Bt,
    const float* __restrict__ b0, const float* __restrict__ b1,
    const float* __restrict__ b2,
    void* __restrict__ outp, int M, int N, int K) {
  __shared__ __align__(16) unsigned short lA[128 * 32];
  __shared__ __align__(16) unsigned short lB[128 * 32];
  const int tid = threadIdx.x;
  const int m0 = blockIdx.y * 128, n0 = blockIdx.x * 128;
  const int lane = tid & 63, wid = tid >> 6;
  const int wr = wid >> 1, wc = wid & 1;
  const int fr = lane & 15, g = lane >> 4;

  const int srow = wid * 32 + (lane >> 2);
  const int scol = (lane & 3) * 8;
  const unsigned short* gA = A + (size_t)(m0 + srow) * K + scol;
  const unsigned short* gB = Bt + (size_t)(n0 + srow) * K + scol;
  unsigned short* lAw = lA + wid * 1024;
  unsigned short* lBw = lB + wid * 1024;

  f32x4 acc[4][4];
#pragma unroll
  for (int i = 0; i < 4; ++i)
#pragma unroll
    for (int j = 0; j < 4; ++j) acc[i][j] = (f32x4){0.f, 0.f, 0.f, 0.f};

  for (int kt = 0; kt < K; kt += 32) {
    gll16(gA + kt, lAw);
    gll16(gA + (size_t)16 * K + kt, lAw + 512);
    gll16(gB + kt, lBw);
    gll16(gB + (size_t)16 * K + kt, lBw + 512);
    __syncthreads();
    bf16x8 af[4], bfv[4];
#pragma unroll
    for (int i = 0; i < 4; ++i)
      af[i] = *reinterpret_cast<const bf16x8*>(
          &lA[(wr * 64 + i * 16 + fr) * 32 + g * 8]);
#pragma unroll
    for (int j = 0; j < 4; ++j)
      bfv[j] = *reinterpret_cast<const bf16x8*>(
          &lB[(wc * 64 + j * 16 + fr) * 32 + g * 8]);
#pragma unroll
    for (int i = 0; i < 4; ++i)
#pragma unroll
      for (int j = 0; j < 4; ++j)
        acc[i][j] = mfma16(af[i], bfv[j], acc[i][j]);
    __syncthreads();
  }

  const int src = n0 >> 10;
  const float* bp = (MODE == 2) ? b0 : (src == 0 ? b0 : (src == 1 ? b1 : b2));
#pragma unroll
  for (int i = 0; i < 4; ++i)
#pragma unroll
    for (int j = 0; j < 4; ++j)
#pragma unroll
      for (int r = 0; r < 4; ++r) {
        int m = m0 + wr * 64 + i * 16 + g * 4 + r;
        int n = n0 + wc * 64 + j * 16 + fr;
        if (MODE == 2) {
          float val = acc[i][j][r] + bp[n];
          reinterpret_cast<float*>(outp)[(size_t)m * N + n] = val;
        } else {
          int within = n & 1023;
          float val = acc[i][j][r] + bp[within];
          if (src == 0) val *= 0.1803368867f;  // 0.125 * log2(e)
          int b = m >> 11, s = m & 2047;
          int hh = within >> 6, dh = within & 63;
          size_t idx;
          if (src != 2)
            idx = ((size_t)(b * NHEADS + hh) * SEQ + s) * HDIM + dh;
          else
            idx = ((size_t)(b * NHEADS + hh) * HDIM + dh) * SEQ + s;
          reinterpret_cast<unsigned short*>(outp)[(size_t)src * CHELEM + idx] =
              f2bf(val);
        }
      }
}

// Flash attention, block-cooperative LDS-staged K/V (round-12 proven
// skeleton) + f32 P tile (convert-on-PV-read via compiler cvt_pk) +
// exp2-domain softmax (scale folded into Q projection).
// Q,K: [B,H,S,64] bf16 ; Vt: [B,H,64,S] bf16 ; O: [B,S,1024] bf16
__global__ __launch_bounds__(256) void attn_fwd10(
    const unsigned short* __restrict__ Q,
    const unsigned short* __restrict__ Km,
    const unsigned short* __restrict__ Vt,
    unsigned short* __restrict__ O) {
  const int tid = threadIdx.x;
  const int lane = tid & 63, wid = tid >> 6;
  const int fr = lane & 15, g = lane >> 4;
  // XCD-grouped decode: lin%8 = XCD; 16 blocks per (b,h) slab on one XCD.
  const int lin = blockIdx.x;            // 0..511
  const int c = lin & 7;
  const int t = lin >> 3;                // 0..63
  const int j = t & 15;                  // block's pair index 0..15
  const int sgrp = t >> 4;               // 0..3
  const int slab = sgrp * 8 + c;         // 0..31
  const int b = slab >> 4, h = slab & 15;
  const int bh = b * NHEADS + h;

  __shared__ __align__(16) unsigned short lK[2][4096];   // 2 x 8KB, swizzled
  __shared__ __align__(16) unsigned short lV[2][4096];   // 2 x 8KB, swizzled
  __shared__ __align__(16) char plf[4][16 * 272];        // f32 P, 272B rows
  char* plw = plf[wid];

  const unsigned short* kptr = Km + (size_t)bh * SEQ * HDIM;
  const unsigned short* vptr = Vt + (size_t)bh * HDIM * SEQ;

  const int sr0 = tid >> 3;              // 0..31
  const int sch = tid & 7;
  const int schx = ((sch ^ (sr0 & 7)) << 3);  // elem offset of 16B chunk
  const int kswz0 = ((g ^ (fr & 7)) << 3);        // ch = g
  const int kswz1 = (((4 + g) ^ (fr & 7)) << 3);  // ch = 4+g

#define STAGE(BI, N0)                                                       \
  { gll16(kptr + (size_t)((N0) + sr0) * HDIM + schx, &lK[BI][wid * 512]);   \
    gll16(kptr + (size_t)((N0) + sr0 + 32) * HDIM + schx,                   \
          &lK[BI][2048 + wid * 512]);                                       \
    gll16(vptr + (size_t)sr0 * SEQ + (N0) + schx, &lV[BI][wid * 512]);      \
    gll16(vptr + (size_t)(sr0 + 32) * SEQ + (N0) + schx,                    \
          &lV[BI][2048 + wid * 512]); }

#pragma unroll 1
  for (int pass = 0; pass < 2; ++pass) {
    const int qt = pass ? (124 - 4 * j + wid) : (4 * j + wid);
    const int q0 = qt * 16;
    const int nkt = pass ? (32 - j) : (j + 1);  // same for all 4 waves

    const unsigned short* qb = Q + ((size_t)bh * SEQ + q0 + fr) * HDIM + g * 8;
    bf16x8 qa0 = *reinterpret_cast<const bf16x8*>(qb);
    bf16x8 qa1 = *reinterpret_cast<const bf16x8*>(qb + 32);

    f32x4 oacc[4];
#pragma unroll
    for (int i = 0; i < 4; ++i) oacc[i] = (f32x4){0.f, 0.f, 0.f, 0.f};
    float mreg[4] = {-3e30f, -3e30f, -3e30f, -3e30f};
    float lrow[4] = {0.f, 0.f, 0.f, 0.f};
    float mtile = -3e30f;

    STAGE(0, 0);
    __syncthreads();

    for (int kt = 0; kt < nkt; ++kt) {
      const int bi = kt & 1;
      if (kt + 1 < nkt) STAGE(bi ^ 1, (kt + 1) * 64);
      const int n0 = kt * 64;
      bf16x8 kf0[4], kf1[4];
#pragma unroll
      for (int cc = 0; cc < 4; ++cc) {
        kf0[cc] = *reinterpret_cast<const bf16x8*>(
            &lK[bi][(cc * 16 + fr) * 64 + kswz0]);
        kf1[cc] = *reinterpret_cast<const bf16x8*>(
            &lK[bi][(cc * 16 + fr) * 64 + kswz1]);
      }
      f32x4 s[4];
#pragma unroll
      for (int cc = 0; cc < 4; ++cc) {
        s[cc] = (f32x4){0.f, 0.f, 0.f, 0.f};
        s[cc] = mfma16(qa0, kf0[cc], s[cc]);
        s[cc] = mfma16(qa1, kf1[cc], s[cc]);
      }
      // (last-tile-only) mask, per-lane max (log2 domain)
      float sv[4][4];
      float lmax = -3e30f;
      if (kt == nkt - 1) {
#pragma unroll
        for (int cc = 0; cc < 4; ++cc)
#pragma unroll
          for (int r = 0; r < 4; ++r) {
            sv[cc][r] = (n0 + cc * 16 + fr <= q0 + g * 4 + r) ? s[cc][r]
                                                              : -1e30f;
            lmax = fmaxf(lmax, sv[cc][r]);
          }
      } else {
#pragma unroll
        for (int cc = 0; cc < 4; ++cc)
#pragma unroll
          for (int r = 0; r < 4; ++r) {
            sv[cc][r] = s[cc][r];
            lmax = fmaxf(lmax, sv[cc][r]);
          }
      }
      // defer-max rescale (rare path); 11.5/log2e == 8 nats (proven bound)
      if (!__all(lmax - mtile <= 11.5f)) {
#pragma unroll
        for (int r = 0; r < 4; ++r) {
          float tm = fmaxf(fmaxf(sv[0][r], sv[1][r]), fmaxf(sv[2][r], sv[3][r]));
#pragma unroll
          for (int msk = 1; msk < 16; msk <<= 1)
            tm = fmaxf(tm, __shfl_xor(tm, msk, 64));
          const float mn = fmaxf(mreg[r], tm);
          const float al = fexp2(mreg[r] - mn);
          mreg[r] = mn;
          lrow[r] *= al;
#pragma unroll
          for (int nf = 0; nf < 4; ++nf) oacc[nf][r] *= al;
        }
        mtile = fminf(fminf(mreg[0], mreg[1]), fminf(mreg[2], mreg[3]));
      }
      // P = 2^(sv - m) stored as f32 (no conversion on write path)
#pragma unroll
      for (int r = 0; r < 4; ++r) {
        const int rl = g * 4 + r;
#pragma unroll
        for (int cc = 0; cc < 4; ++cc) {
          float p = fexp2(sv[cc][r] - mreg[r]);
          lrow[r] += p;
          *reinterpret_cast<float*>(plw + rl * 272 + (cc * 16 + fr) * 4) = p;
        }
      }
      // PV: A-frag read as f32, converted via paired v_cvt_pk_bf16_f32
#pragma unroll
      for (int blk = 0; blk < 2; ++blk) {
        const int abase = fr * 272 + blk * 128 + g * 32;
        f32x4 lo = *reinterpret_cast<const f32x4*>(plw + abase);
        f32x4 hi = *reinterpret_cast<const f32x4*>(plw + abase + 16);
        union { __bf16 e[8]; bf16x8 v; } cu;
#pragma unroll
        for (int t2 = 0; t2 < 4; ++t2) {
          cu.e[t2] = (__bf16)lo[t2];
          cu.e[4 + t2] = (__bf16)hi[t2];
        }
        bf16x8 pa = cu.v;
        const int vs = blk ? kswz1 : kswz0;
#pragma unroll
        for (int nf = 0; nf < 4; ++nf) {
          bf16x8 vfr = *reinterpret_cast<const bf16x8*>(
              &lV[bi][(nf * 16 + fr) * 64 + vs]);
          oacc[nf] = mfma16(pa, vfr, oacc[nf]);
        }
      }
      __syncthreads();  // staged kt+1 complete; reads of buf bi done
    }

#pragma unroll
    for (int r = 0; r < 4; ++r) {
      float ls = lrow[r];
#pragma unroll
      for (int msk = 1; msk < 16; msk <<= 1) ls += __shfl_xor(ls, msk, 64);
      const float inv = 1.f / ls;
      const size_t base =
          ((size_t)b * SEQ + q0 + g * 4 + r) * D_MODEL + h * HDIM;
#pragma unroll
      for (int nf = 0; nf < 4; ++nf)
        O[base + nf * 16 + fr] = f2bf(oacc[nf][r] * inv);
    }
  }
#undef STAGE
}

extern "C" void kernel_launch(void* const* d_in, const int* in_sizes, int n_in,
                              void* d_out, int out_size, void* d_ws,
                              size_t ws_size, hipStream_t stream) {
  const float* x  = (const float*)d_in[0];
  const float* wq = (const float*)d_in[1];
  const float* bq = (const float*)d_in[2];
  const float* wk = (const float*)d_in[3];
  const float* bk = (const float*)d_in[4];
  const float* wv = (const float*)d_in[5];
  const float* bv = (const float*)d_in[6];
  const float* wo = (const float*)d_in[7];
  const float* bo = (const float*)d_in[8];
  float* out = (float*)d_out;

  char* w = (char*)d_ws;
  unsigned short* xb    = (unsigned short*)w; w += (size_t)MROWS * D_MODEL * 2;
  unsigned short* wqkvb = (unsigned short*)w; w += (size_t)3 * D_MODEL * D_MODEL * 2;
  unsigned short* wob   = (unsigned short*)w; w += (size_t)D_MODEL * D_MODEL * 2;
  unsigned short* Qb    = (unsigned short*)w; w += CHELEM * 2 * 3;  // Q,K,Vt
  unsigned short* Ob    = (unsigned short*)w; w += (size_t)MROWS * D_MODEL * 2;
  unsigned short* Kb  = Qb + CHELEM;
  unsigned short* Vtb = Qb + 2 * CHELEM;

  {
    int n4 = MROWS * D_MODEL / 4;
    cvt_f32_bf16<<<n4 / 256, 256, 0, stream>>>(x, xb, n4);
  }
  {
    int n4 = D_MODEL * D_MODEL / 4;  // 262144 -> 1024 blocks x 4
    cvt_w4<<<dim3(n4 / 256, 4), 256, 0, stream>>>(
        wq, wk, wv, wo, wqkvb, wqkvb + (size_t)D_MODEL * D_MODEL,
        wqkvb + (size_t)2 * D_MODEL * D_MODEL, wob);
  }

  // fused QKV projection: N = 3072
  gemm_bt2<3><<<dim3(3 * D_MODEL / 128, MROWS / 128), 256, 0, stream>>>(
      xb, wqkvb, bq, bk, bv, Qb, MROWS, 3 * D_MODEL, D_MODEL);

  attn_fwd10<<<512, 256, 0, stream>>>(Qb, Kb, Vtb, Ob);

  gemm_bt2<2><<<dim3(D_MODEL / 128, MROWS / 128), 256, 0, stream>>>(
      Ob, wob, bo, bo, bo, out, MROWS, D_MODEL, D_MODEL);
}